// Round 4
// baseline (665.965 us; speedup 1.0000x reference)
//
#include <hip/hip_runtime.h>

#define Bc 8
#define Sc 256
#define Hc 128
#define HDc 32
#define NHc 4
#define SCALE 0.17677669529663687f
#define CROWS 32                 // rows per DMA chunk
#define NCH (Sc / CROWS)         // 8 chunks per head
#define NFC (NHc * NCH)          // 32 flat chunks
#define CBYTES (CROWS * Hc * 4)  // 16384 B per chunk

#define GLB(p) ((const __attribute__((address_space(1))) void*)(p))
#define LDS(p) ((__attribute__((address_space(3))) void*)(p))

__global__ __launch_bounds__(256) void mmha_kernel(
    const float* __restrict__ hs,
    const float* __restrict__ am,
    const float* __restrict__ abs0,
    const float* __restrict__ abs1,
    const float* __restrict__ rel0,
    const float* __restrict__ rel1,
    const float* __restrict__ Wq, const float* __restrict__ bq,
    const float* __restrict__ Wk, const float* __restrict__ bk,
    const float* __restrict__ Wv, const float* __restrict__ bv,
    const float* __restrict__ Wo, const float* __restrict__ bo,
    float* __restrict__ out)
{
    const int t = threadIdx.x;
    const int bqi = blockIdx.x;        // 0..2047
    const int b = bqi >> 8;
    const int q = bqi & 255;
    const int lane = t & 63;           // lane within wave
    const int wv = t >> 6;             // wave 0..3
    const int c4 = t & 31;             // channel quad
    const int part = t >> 5;           // row-part 0..7

    __shared__ __align__(16) float ebuf[2][CROWS * Hc];   // 32 KB double buffer
    __shared__ float hsrow[Hc];
    __shared__ float Qrow[Hc];
    __shared__ float qk_sh[NHc * Hc];
    __shared__ float cb_sh[NHc];
    __shared__ float mask_row[Sc];
    __shared__ float4 red4[256];
    __shared__ float l_sh[8];
    __shared__ float rbarn[Hc];
    __shared__ float ctx_sh[Hc];

    const size_t rowbase = (size_t)(b * Sc + q) * Hc;
    const size_t bsh  = (size_t)b * Sc * Hc;
    const size_t bqsh = (size_t)(b * Sc + q) * Sc * Hc;

    // ---- stage hidden row + mask row ----
    if (t < Hc) hsrow[t] = hs[rowbase + t];
    mask_row[t] = am[((size_t)(b * Sc) + q) * Sc + t];
    __syncthreads();

    // ---- Qrow[t] = bq[t] + hsrow · Wq[:,t] ----
    if (t < Hc) {
        float acc = bq[t];
        #pragma unroll 16
        for (int c = 0; c < Hc; ++c) acc += hsrow[c] * Wq[c * Hc + t];
        Qrow[t] = acc;
    }
    __syncthreads();

    // ---- cbias_h = 2 * Q_h · bk_h ----
    if (t < Hc) {
        float pv = Qrow[t] * bk[t];
        #pragma unroll
        for (int off = 16; off >= 1; off >>= 1) pv += __shfl_xor(pv, off, 32);
        if ((t & 31) == 0) cb_sh[t >> 5] = 2.0f * pv;
    }
    // ---- qk_h[c'] = Wk[c', h*32:(h+1)*32] · Q_h ----
    for (int rep = 0; rep < 2; ++rep) {
        int idx = rep * 256 + t;
        int h = idx >> 7, cp = idx & 127;
        const float4* wkr = (const float4*)(Wk + cp * Hc + h * HDc);
        const float4* qr  = (const float4*)(Qrow + h * HDc);
        float acc = 0.f;
        #pragma unroll
        for (int j = 0; j < HDc / 4; ++j) {
            float4 wvv = wkr[j];
            float4 qv = qr[j];
            acc += wvv.x * qv.x + wvv.y * qv.y + wvv.z * qv.z + wvv.w * qv.w;
        }
        qk_sh[h * Hc + cp] = acc;
    }
    __syncthreads();

    const float* e_abs0 = abs0 + bsh;
    const float* e_abs1 = abs1 + bsh;
    const float* e_rel0 = rel0 + bqsh;
    const float* e_rel1 = rel1 + bqsh;

    auto cbase = [&](int fc) -> const char* {
        const int hh = fc >> 3;
        const float* base = (hh == 0) ? e_abs0 : (hh == 1) ? e_abs1
                          : (hh == 2) ? e_rel0 : e_rel1;
        return (const char*)base + (size_t)(fc & 7) * CBYTES;
    };
    // Each wave DMAs 4 KB (4 × 1-KB segments) of the 16-KB chunk.
    auto dma = [&](int fc) {
        const char* g = cbase(fc);
        float* lb = ebuf[fc & 1];
        #pragma unroll
        for (int i = 0; i < 4; ++i) {
            const int s = wv * 4 + i;
            __builtin_amdgcn_global_load_lds(GLB(g + s * 1024 + lane * 16),
                                             LDS(lb + s * 256), 16, 0, 0);
        }
    };

    dma(0);
    const float4* hs4 = (const float4*)(hs + bsh);

    for (int h = 0; h < NHc; ++h) {
        const float4 qreg = ((const float4*)(qk_sh + h * Hc))[c4];
        const float cb = cb_sh[h];
        float4 acc; acc.x = acc.y = acc.z = acc.w = 0.f;
        float l = 0.f;

        for (int cc = 0; cc < NCH; ++cc) {
            const int fc = h * NCH + cc;
            // Barrier BEFORE next DMA issue: drains only chunk fc's DMA
            // (issued one full compute-phase ago) -> compute(fc) overlaps
            // DMA(fc+1).
            __syncthreads();
            const int k0 = cc * CROWS;
            // hs loads issued BEFORE the DMA so their vmcnt waits don't
            // force draining the younger DMA instructions.
            float4 a0 = hs4[(size_t)(k0 +      part) * (Hc / 4) + c4];
            float4 a1 = hs4[(size_t)(k0 +  8 + part) * (Hc / 4) + c4];
            float4 a2 = hs4[(size_t)(k0 + 16 + part) * (Hc / 4) + c4];
            float4 a3 = hs4[(size_t)(k0 + 24 + part) * (Hc / 4) + c4];
            if (fc + 1 < NFC) dma(fc + 1);

            const float4* eb4 = (const float4*)ebuf[fc & 1];
            #pragma unroll
            for (int j = 0; j < 4; ++j) {
                const int lr = j * 8 + part;
                const float4 a = (j == 0) ? a0 : (j == 1) ? a1 : (j == 2) ? a2 : a3;
                const float4 e = eb4[lr * (Hc / 4) + c4];
                float4 v;
                v.x = a.x + e.x; v.y = a.y + e.y;
                v.z = a.z + e.z; v.w = a.w + e.w;
                float pv = v.x * qreg.x + v.y * qreg.y + v.z * qreg.z + v.w * qreg.w;
                #pragma unroll
                for (int off2 = 16; off2 >= 1; off2 >>= 1) pv += __shfl_xor(pv, off2, 32);
                const float p = __expf((pv + cb) * SCALE + mask_row[k0 + lr]);
                l += p;
                acc.x += p * v.x; acc.y += p * v.y;
                acc.z += p * v.z; acc.w += p * v.w;
            }
        }

        // ---- per-head epilogue: reduce rbar across the 8 row-parts ----
        red4[t] = acc;
        if (c4 == 0) l_sh[part] = l;
        __syncthreads();
        if (t < 32) {
            float4 tot; tot.x = tot.y = tot.z = tot.w = 0.f;
            #pragma unroll
            for (int g = 0; g < 8; ++g) {
                float4 v = red4[g * 32 + t];
                tot.x += v.x; tot.y += v.y; tot.z += v.z; tot.w += v.w;
            }
            float lt = 0.f;
            #pragma unroll
            for (int g = 0; g < 8; ++g) lt += l_sh[g];
            const float inv = 1.0f / lt;
            float4 r; r.x = tot.x * inv; r.y = tot.y * inv;
                      r.z = tot.z * inv; r.w = tot.w * inv;
            ((float4*)rbarn)[t] = r;
        }
        __syncthreads();
        if (t < 32) {
            float cv = 2.0f * bv[h * HDc + t];
            #pragma unroll 8
            for (int c = 0; c < Hc; ++c) cv += rbarn[c] * Wv[c * Hc + h * HDc + t];
            ctx_sh[h * HDc + t] = cv;
        }
        __syncthreads();
    }

    // ---- out[b,q,t] = bo[t] + ctx · Wo[:,t] ----
    if (t < Hc) {
        float ov = bo[t];
        #pragma unroll 16
        for (int c = 0; c < Hc; ++c) ov += ctx_sh[c] * Wo[c * Hc + t];
        out[rowbase + t] = ov;
    }
}

extern "C" void kernel_launch(void* const* d_in, const int* in_sizes, int n_in,
                              void* d_out, int out_size, void* d_ws, size_t ws_size,
                              hipStream_t stream) {
    const float* hs = (const float*)d_in[0];
    const float* am = (const float*)d_in[1];
    const float* a0 = (const float*)d_in[2];
    const float* a1 = (const float*)d_in[3];
    const float* r0 = (const float*)d_in[4];
    const float* r1 = (const float*)d_in[5];
    const float* Wq = (const float*)d_in[6];
    const float* bq = (const float*)d_in[7];
    const float* Wk = (const float*)d_in[8];
    const float* bk = (const float*)d_in[9];
    const float* Wv = (const float*)d_in[10];
    const float* bv = (const float*)d_in[11];
    const float* Wo = (const float*)d_in[12];
    const float* bo = (const float*)d_in[13];

    mmha_kernel<<<dim3(Bc * Sc), dim3(256), 0, stream>>>(
        hs, am, a0, a1, r0, r1, Wq, bq, Wk, bk, Wv, bv, Wo, bo, (float*)d_out);
}